// Round 5
// baseline (194.032 us; speedup 1.0000x reference)
//
#include <hip/hip_runtime.h>

// Reprojection residual for bundle adjustment.
// out[i] = project(points_3d[pt_idx[i]], camera_params[cam_idx[i]]) - points_2d[i]
//
// NUMERICS: harness reference is float64; output is amplified ~proj^5 with
// |Z| down to ~1e-4, so the projection runs in double precision and only the
// final residual rounds to fp32 (absmax 3.6e16 vs threshold 9.9e16, passing
// since round 2). The f64 op sequence below must stay byte-identical.
//
// ROUND 5: MLP experiment. 4 obs/thread with all point-gathers issued before
// compute (2x deeper memory-level parallelism than before), no LDS camera
// stage (camera table is L2-resident; divergent L1 probes ~= LDS bank
// conflicts), 256-thread blocks, non-temporal streaming loads/stores.
// Discriminates latency-bound (expect ~100-115 us) vs random-line
// request/BW wall (flat ~145 us => roofline).
//
// Inputs (setup_inputs order):
//   d_in[0] points_2d      float32 (N_OBS, 2)
//   d_in[1] camera_indices int32   (N_OBS,)
//   d_in[2] point_indices  int32   (N_OBS,)
//   d_in[3] camera_params  float32 (N_CAM, 10)  [qw qx qy qz tx ty tz f k1 k2]
//   d_in[4] points_3d      float32 (N_PTS, 3)
// Output: float32 (N_OBS, 2)

typedef __attribute__((ext_vector_type(4))) float f32x4;
typedef __attribute__((ext_vector_type(4))) int   i32x4;

__global__ void repack_pts_kernel(const float* __restrict__ pts,
                                  f32x4* __restrict__ out, int npts) {
    int i = blockIdx.x * blockDim.x + threadIdx.x;
    if (i < npts) {
        const float* p = pts + (size_t)i * 3;
        f32x4 v = {p[0], p[1], p[2], 0.0f};
        __builtin_nontemporal_store(v, out + i);
    }
}

// f64 projection; identical arithmetic sequence to the passing round-2 kernel.
__device__ __forceinline__ float2 project_one(
    const float* __restrict__ cams, int ci,
    float pxf, float pyf, float pzf,
    float obsx, float obsy)
{
    const float2* cl = reinterpret_cast<const float2*>(cams + (size_t)ci * 10);
    float2 c01 = cl[0];  // qw qx
    float2 c23 = cl[1];  // qy qz
    float2 c45 = cl[2];  // tx ty
    float2 c67 = cl[3];  // tz f
    float2 c89 = cl[4];  // k1 k2

    double px = (double)pxf, py = (double)pyf, pz = (double)pzf;
    double qw = (double)c01.x, qx = (double)c01.y;
    double qy = (double)c23.x, qz = (double)c23.y;

    double nrm2 = qw * qw + qx * qx + qy * qy + qz * qz;
    double s = 1.0 / sqrt(nrm2);
    double w  = qw * s;
    double vx = qx * s, vy = qy * s, vz = qz * s;

    double tx = (vy * pz - vz * py) + w * px;
    double ty = (vz * px - vx * pz) + w * py;
    double tz = (vx * py - vy * px) + w * pz;

    double X = (px + 2.0 * (vy * tz - vz * ty)) + (double)c45.x;
    double Y = (py + 2.0 * (vz * tx - vx * tz)) + (double)c45.y;
    double Z = (pz + 2.0 * (vx * ty - vy * tx)) + (double)c67.x;

    double rz  = 1.0 / Z;
    double prx = -X * rz;
    double pry = -Y * rz;

    double f  = (double)c67.y;
    double k1 = (double)c89.x, k2 = (double)c89.y;

    double nn = prx * prx + pry * pry;
    double r  = 1.0 + k1 * nn + k2 * nn * nn;
    double rf = r * f;

    float2 o;
    o.x = (float)(prx * rf - (double)obsx);
    o.y = (float)(pry * rf - (double)obsy);
    return o;
}

__global__ __launch_bounds__(256) void reproj_kernel(
    const f32x4*  __restrict__ p2d4,       // 2 observations per float4
    const int*    __restrict__ cam_idx,
    const int*    __restrict__ pt_idx,
    const float*  __restrict__ cams,
    const float*  __restrict__ pts_raw,    // fallback
    const f32x4*  __restrict__ pts_packed, // 16B-aligned points (or null)
    f32x4*        __restrict__ out4,
    int n)
{
    int base = (blockIdx.x * blockDim.x + threadIdx.x) * 4;

    if (base + 3 < n) {
        // ---- issue ALL independent loads first (MLP) ----
        i32x4 ci = __builtin_nontemporal_load(
            reinterpret_cast<const i32x4*>(cam_idx + base));
        i32x4 pi = __builtin_nontemporal_load(
            reinterpret_cast<const i32x4*>(pt_idx + base));

        f32x4 p0, p1, p2, p3;
        if (pts_packed) {
            p0 = pts_packed[pi.x];
            p1 = pts_packed[pi.y];
            p2 = pts_packed[pi.z];
            p3 = pts_packed[pi.w];
        } else {
            const float* a = pts_raw + (size_t)pi.x * 3;
            const float* b = pts_raw + (size_t)pi.y * 3;
            const float* c = pts_raw + (size_t)pi.z * 3;
            const float* d = pts_raw + (size_t)pi.w * 3;
            p0 = {a[0], a[1], a[2], 0.f};
            p1 = {b[0], b[1], b[2], 0.f};
            p2 = {c[0], c[1], c[2], 0.f};
            p3 = {d[0], d[1], d[2], 0.f};
        }

        f32x4 obA = __builtin_nontemporal_load(p2d4 + (base >> 1));
        f32x4 obB = __builtin_nontemporal_load(p2d4 + (base >> 1) + 1);

        // ---- compute 4 observations ----
        float2 o0 = project_one(cams, ci.x, p0.x, p0.y, p0.z, obA.x, obA.y);
        float2 o1 = project_one(cams, ci.y, p1.x, p1.y, p1.z, obA.z, obA.w);
        f32x4 ovA = {o0.x, o0.y, o1.x, o1.y};
        __builtin_nontemporal_store(ovA, out4 + (base >> 1));

        float2 o2 = project_one(cams, ci.z, p2.x, p2.y, p2.z, obB.x, obB.y);
        float2 o3 = project_one(cams, ci.w, p3.x, p3.y, p3.z, obB.z, obB.w);
        f32x4 ovB = {o2.x, o2.y, o3.x, o3.y};
        __builtin_nontemporal_store(ovB, out4 + (base >> 1) + 1);
    } else {
        const float* p2 = reinterpret_cast<const float*>(p2d4);
        float* po = reinterpret_cast<float*>(out4);
        for (int i = base; i < n; ++i) {
            int ci = cam_idx[i];
            int pi = pt_idx[i];
            float ax, ay, az;
            if (pts_packed) {
                f32x4 pa = pts_packed[pi];
                ax = pa.x; ay = pa.y; az = pa.z;
            } else {
                const float* pA = pts_raw + (size_t)pi * 3;
                ax = pA[0]; ay = pA[1]; az = pA[2];
            }
            float2 o = project_one(cams, ci, ax, ay, az,
                                   p2[2 * i], p2[2 * i + 1]);
            po[2 * i]     = o.x;
            po[2 * i + 1] = o.y;
        }
    }
}

extern "C" void kernel_launch(void* const* d_in, const int* in_sizes, int n_in,
                              void* d_out, int out_size, void* d_ws, size_t ws_size,
                              hipStream_t stream) {
    const float* p2d     = (const float*)d_in[0];
    const int*   cam_idx = (const int*)d_in[1];
    const int*   pt_idx  = (const int*)d_in[2];
    const float* cams    = (const float*)d_in[3];
    const float* pts     = (const float*)d_in[4];

    int n    = in_sizes[1];      // N_OBS
    int npts = in_sizes[4] / 3;  // N_PTS

    f32x4* packed = nullptr;
    if (ws_size >= (size_t)npts * 16) {
        packed = (f32x4*)d_ws;
        int t = 256;
        int b = (npts + t - 1) / t;
        repack_pts_kernel<<<b, t, 0, stream>>>(pts, packed, npts);
    }

    int threads = 256;
    int per_block = threads * 4;
    int blocks = (n + per_block - 1) / per_block;

    reproj_kernel<<<blocks, threads, 0, stream>>>(
        (const f32x4*)p2d, cam_idx, pt_idx, cams, pts, packed,
        (f32x4*)d_out, n);
}

// Round 6
// 140.050 us; speedup vs baseline: 1.3854x; 1.3854x over previous
//
#include <hip/hip_runtime.h>

// Reprojection residual for bundle adjustment.
// out[i] = project(points_3d[pt_idx[i]], camera_params[cam_idx[i]]) - points_2d[i]
//
// NUMERICS: harness reference is float64; output is amplified ~proj^5 with
// |Z| down to ~1e-4, so the projection runs in double precision and only the
// final residual rounds to fp32 (absmax 3.60288e16 vs threshold 9.9e16,
// passing since round 2). The f64 op sequence below is frozen.
//
// ROUND 6: union of measured winners under the scored (graph-replay) metric:
//   - LDS camera table (80 KB): replaces 5 divergent global loads/obs
//     (~64-probe TA serialization each) with ds_read (~7 us total conflict
//     cost). Profiled win r3->r4: 180->145 us.
//   - NO repack kernel: it cost +10 us per call in the scored graph; the
//     12-B point records are gathered with 3 dwords (same 64-B line).
//   - non-temporal LOADS on the streamed inputs (don't evict the point
//     table from L2); PLAIN stores (NT stores write half-line stripes ->
//     2x WRITE_SIZE, the round-5 regression).
//   - 1024-thread blocks, 2 obs/thread: 2 blocks/CU -> full 32-wave
//     occupancy, amortizes the LDS stage.
//
// Inputs (setup_inputs order):
//   d_in[0] points_2d      float32 (N_OBS, 2)
//   d_in[1] camera_indices int32   (N_OBS,)
//   d_in[2] point_indices  int32   (N_OBS,)
//   d_in[3] camera_params  float32 (N_CAM, 10)  [qw qx qy qz tx ty tz f k1 k2]
//   d_in[4] points_3d      float32 (N_PTS, 3)
// Output: float32 (N_OBS, 2)

typedef __attribute__((ext_vector_type(4))) float f32x4;
typedef __attribute__((ext_vector_type(2))) int   i32x2;

#define MAX_CAM_WORDS 20000   // 2000 cameras * 10 floats = 80 KB LDS

// f64 projection; camera params from LDS. Frozen arithmetic sequence.
__device__ __forceinline__ float2 project_one(
    const float* lds_cams, int ci,
    float pxf, float pyf, float pzf,
    float obsx, float obsy)
{
    const float2* cl = reinterpret_cast<const float2*>(lds_cams + ci * 10);
    float2 c01 = cl[0];  // qw qx
    float2 c23 = cl[1];  // qy qz
    float2 c45 = cl[2];  // tx ty
    float2 c67 = cl[3];  // tz f
    float2 c89 = cl[4];  // k1 k2

    double px = (double)pxf, py = (double)pyf, pz = (double)pzf;
    double qw = (double)c01.x, qx = (double)c01.y;
    double qy = (double)c23.x, qz = (double)c23.y;

    double nrm2 = qw * qw + qx * qx + qy * qy + qz * qz;
    double s = 1.0 / sqrt(nrm2);
    double w  = qw * s;
    double vx = qx * s, vy = qy * s, vz = qz * s;

    double tx = (vy * pz - vz * py) + w * px;
    double ty = (vz * px - vx * pz) + w * py;
    double tz = (vx * py - vy * px) + w * pz;

    double X = (px + 2.0 * (vy * tz - vz * ty)) + (double)c45.x;
    double Y = (py + 2.0 * (vz * tx - vx * tz)) + (double)c45.y;
    double Z = (pz + 2.0 * (vx * ty - vy * tx)) + (double)c67.x;

    double rz  = 1.0 / Z;
    double prx = -X * rz;
    double pry = -Y * rz;

    double f  = (double)c67.y;
    double k1 = (double)c89.x, k2 = (double)c89.y;

    double nn = prx * prx + pry * pry;
    double r  = 1.0 + k1 * nn + k2 * nn * nn;
    double rf = r * f;

    float2 o;
    o.x = (float)(prx * rf - (double)obsx);
    o.y = (float)(pry * rf - (double)obsy);
    return o;
}

__global__ __launch_bounds__(1024, 8) void reproj_kernel(
    const f32x4*  __restrict__ p2d4,      // 2 observations per float4
    const int*    __restrict__ cam_idx,
    const int*    __restrict__ pt_idx,
    const float*  __restrict__ cams,
    const float*  __restrict__ pts,       // raw (N_PTS,3) float32
    f32x4*        __restrict__ out4,
    int n, int ncam_words)
{
    __shared__ float lds_cams[MAX_CAM_WORDS];

    // cooperative stage: 80 KB, coalesced float4 loads + b128 LDS writes
    {
        int nv = ncam_words >> 2;
        if (nv > (MAX_CAM_WORDS >> 2)) nv = MAX_CAM_WORDS >> 2;
        const f32x4* src = reinterpret_cast<const f32x4*>(cams);
        f32x4* dst = reinterpret_cast<f32x4*>(lds_cams);
        for (int j = threadIdx.x; j < nv; j += blockDim.x)
            dst[j] = src[j];
        for (int j = (nv << 2) + threadIdx.x; j < ncam_words && j < MAX_CAM_WORDS;
             j += blockDim.x)
            lds_cams[j] = cams[j];
    }
    __syncthreads();

    int i = (blockIdx.x * blockDim.x + threadIdx.x) * 2;
    if (i + 1 < n) {
        i32x2 ci = __builtin_nontemporal_load(
            reinterpret_cast<const i32x2*>(cam_idx + i));
        i32x2 pi = __builtin_nontemporal_load(
            reinterpret_cast<const i32x2*>(pt_idx + i));
        f32x4 ob = __builtin_nontemporal_load(p2d4 + (i >> 1));

        // point gathers: 3 dwords each (12-B record, usually one 64-B line)
        const float* pA = pts + (size_t)pi.x * 3;
        const float* pB = pts + (size_t)pi.y * 3;
        float ax = pA[0], ay = pA[1], az = pA[2];
        float bx = pB[0], by = pB[1], bz = pB[2];

        float2 o0 = project_one(lds_cams, ci.x, ax, ay, az, ob.x, ob.y);
        float2 o1 = project_one(lds_cams, ci.y, bx, by, bz, ob.z, ob.w);
        f32x4 ov = {o0.x, o0.y, o1.x, o1.y};
        out4[i >> 1] = ov;   // plain cached store: L2 write-combines
    } else if (i < n) {
        int ci = cam_idx[i];
        int pi = pt_idx[i];
        const float* pA = pts + (size_t)pi * 3;
        const float* p2 = reinterpret_cast<const float*>(p2d4);
        float2 o = project_one(lds_cams, ci, pA[0], pA[1], pA[2],
                               p2[2 * i], p2[2 * i + 1]);
        float* po = reinterpret_cast<float*>(out4);
        po[2 * i]     = o.x;
        po[2 * i + 1] = o.y;
    }
}

extern "C" void kernel_launch(void* const* d_in, const int* in_sizes, int n_in,
                              void* d_out, int out_size, void* d_ws, size_t ws_size,
                              hipStream_t stream) {
    const float* p2d     = (const float*)d_in[0];
    const int*   cam_idx = (const int*)d_in[1];
    const int*   pt_idx  = (const int*)d_in[2];
    const float* cams    = (const float*)d_in[3];
    const float* pts     = (const float*)d_in[4];

    int n   = in_sizes[1];  // N_OBS
    int ncw = in_sizes[3];  // N_CAM * 10

    int threads = 1024;
    int per_block = threads * 2;
    int blocks = (n + per_block - 1) / per_block;

    reproj_kernel<<<blocks, threads, 0, stream>>>(
        (const f32x4*)p2d, cam_idx, pt_idx, cams, pts,
        (f32x4*)d_out, n, ncw);
}

// Round 7
// 137.729 us; speedup vs baseline: 1.4088x; 1.0169x over previous
//
#include <hip/hip_runtime.h>

// Reprojection residual for bundle adjustment.
// out[i] = project(points_3d[pt_idx[i]], camera_params[cam_idx[i]]) - points_2d[i]
//
// NUMERICS: harness reference is float64; output is amplified ~proj^5 with
// |Z| down to ~1e-4, so the projection runs in double precision and only the
// final residual rounds to fp32 (absmax 3.60288e16 vs threshold 9.9e16,
// passing since round 2). The f64 op sequence below is frozen.
//
// ROUND 7: unconfounded MLP test. Round-5's MLP=4 regression was confounded:
// it simultaneously dropped the LDS camera table (re-adding ~4.7 divergent
// TA probes/obs) and used NT stores (2x WRITE_SIZE). This round keeps the
// r6 winners (LDS cams, plain stores, NT streaming loads, 1024-thread
// blocks) and ONLY deepens per-thread MLP to 4 observations with all 12
// point-gather dwords issued before any f64 compute. r6 accounting shows no
// saturated pipe (VALU 18%, TA ~3cy/obs, L2 0.12 req/cy) => latency-bound;
// doubling in-flight misses should cut toward ~105 us. Flat => structural
// issue-rate wall (roofline).
//
// Inputs (setup_inputs order):
//   d_in[0] points_2d      float32 (N_OBS, 2)
//   d_in[1] camera_indices int32   (N_OBS,)
//   d_in[2] point_indices  int32   (N_OBS,)
//   d_in[3] camera_params  float32 (N_CAM, 10)  [qw qx qy qz tx ty tz f k1 k2]
//   d_in[4] points_3d      float32 (N_PTS, 3)
// Output: float32 (N_OBS, 2)

typedef __attribute__((ext_vector_type(4))) float f32x4;
typedef __attribute__((ext_vector_type(4))) int   i32x4;

#define MAX_CAM_WORDS 20000   // 2000 cameras * 10 floats = 80 KB LDS

// f64 projection; camera params from LDS. Frozen arithmetic sequence.
__device__ __forceinline__ float2 project_one(
    const float* lds_cams, int ci,
    float pxf, float pyf, float pzf,
    float obsx, float obsy)
{
    const float2* cl = reinterpret_cast<const float2*>(lds_cams + ci * 10);
    float2 c01 = cl[0];  // qw qx
    float2 c23 = cl[1];  // qy qz
    float2 c45 = cl[2];  // tx ty
    float2 c67 = cl[3];  // tz f
    float2 c89 = cl[4];  // k1 k2

    double px = (double)pxf, py = (double)pyf, pz = (double)pzf;
    double qw = (double)c01.x, qx = (double)c01.y;
    double qy = (double)c23.x, qz = (double)c23.y;

    double nrm2 = qw * qw + qx * qx + qy * qy + qz * qz;
    double s = 1.0 / sqrt(nrm2);
    double w  = qw * s;
    double vx = qx * s, vy = qy * s, vz = qz * s;

    double tx = (vy * pz - vz * py) + w * px;
    double ty = (vz * px - vx * pz) + w * py;
    double tz = (vx * py - vy * px) + w * pz;

    double X = (px + 2.0 * (vy * tz - vz * ty)) + (double)c45.x;
    double Y = (py + 2.0 * (vz * tx - vx * tz)) + (double)c45.y;
    double Z = (pz + 2.0 * (vx * ty - vy * tx)) + (double)c67.x;

    double rz  = 1.0 / Z;
    double prx = -X * rz;
    double pry = -Y * rz;

    double f  = (double)c67.y;
    double k1 = (double)c89.x, k2 = (double)c89.y;

    double nn = prx * prx + pry * pry;
    double r  = 1.0 + k1 * nn + k2 * nn * nn;
    double rf = r * f;

    float2 o;
    o.x = (float)(prx * rf - (double)obsx);
    o.y = (float)(pry * rf - (double)obsy);
    return o;
}

__global__ __launch_bounds__(1024, 8) void reproj_kernel(
    const f32x4*  __restrict__ p2d4,      // 2 observations per float4
    const int*    __restrict__ cam_idx,
    const int*    __restrict__ pt_idx,
    const float*  __restrict__ cams,
    const float*  __restrict__ pts,       // raw (N_PTS,3) float32
    f32x4*        __restrict__ out4,
    int n, int ncam_words)
{
    __shared__ float lds_cams[MAX_CAM_WORDS];

    // cooperative stage: 80 KB, coalesced float4 loads + b128 LDS writes
    {
        int nv = ncam_words >> 2;
        if (nv > (MAX_CAM_WORDS >> 2)) nv = MAX_CAM_WORDS >> 2;
        const f32x4* src = reinterpret_cast<const f32x4*>(cams);
        f32x4* dst = reinterpret_cast<f32x4*>(lds_cams);
        for (int j = threadIdx.x; j < nv; j += blockDim.x)
            dst[j] = src[j];
        for (int j = (nv << 2) + threadIdx.x; j < ncam_words && j < MAX_CAM_WORDS;
             j += blockDim.x)
            lds_cams[j] = cams[j];
    }
    __syncthreads();

    int base = (blockIdx.x * blockDim.x + threadIdx.x) * 4;

    if (base + 3 < n) {
        // ---- issue ALL independent global loads first (MLP depth 4) ----
        i32x4 pi = __builtin_nontemporal_load(
            reinterpret_cast<const i32x4*>(pt_idx + base));

        // 12 point-gather dwords, all independent, issued back-to-back
        const float* pA = pts + (size_t)pi.x * 3;
        const float* pB = pts + (size_t)pi.y * 3;
        const float* pC = pts + (size_t)pi.z * 3;
        const float* pD = pts + (size_t)pi.w * 3;
        float ax = pA[0], ay = pA[1], az = pA[2];
        float bx = pB[0], by = pB[1], bz = pB[2];
        float cx = pC[0], cy = pC[1], cz = pC[2];
        float dx = pD[0], dy = pD[1], dz = pD[2];

        i32x4 ci = __builtin_nontemporal_load(
            reinterpret_cast<const i32x4*>(cam_idx + base));
        f32x4 obA = __builtin_nontemporal_load(p2d4 + (base >> 1));
        f32x4 obB = __builtin_nontemporal_load(p2d4 + (base >> 1) + 1);

        // ---- compute 4 observations (camera params from LDS) ----
        float2 o0 = project_one(lds_cams, ci.x, ax, ay, az, obA.x, obA.y);
        float2 o1 = project_one(lds_cams, ci.y, bx, by, bz, obA.z, obA.w);
        f32x4 ovA = {o0.x, o0.y, o1.x, o1.y};
        out4[(base >> 1)] = ovA;          // plain cached store

        float2 o2 = project_one(lds_cams, ci.z, cx, cy, cz, obB.x, obB.y);
        float2 o3 = project_one(lds_cams, ci.w, dx, dy, dz, obB.z, obB.w);
        f32x4 ovB = {o2.x, o2.y, o3.x, o3.y};
        out4[(base >> 1) + 1] = ovB;
    } else {
        const float* p2 = reinterpret_cast<const float*>(p2d4);
        float* po = reinterpret_cast<float*>(out4);
        for (int i = base; i < n; ++i) {
            int ci = cam_idx[i];
            int pi = pt_idx[i];
            const float* pA = pts + (size_t)pi * 3;
            float2 o = project_one(lds_cams, ci, pA[0], pA[1], pA[2],
                                   p2[2 * i], p2[2 * i + 1]);
            po[2 * i]     = o.x;
            po[2 * i + 1] = o.y;
        }
    }
}

extern "C" void kernel_launch(void* const* d_in, const int* in_sizes, int n_in,
                              void* d_out, int out_size, void* d_ws, size_t ws_size,
                              hipStream_t stream) {
    const float* p2d     = (const float*)d_in[0];
    const int*   cam_idx = (const int*)d_in[1];
    const int*   pt_idx  = (const int*)d_in[2];
    const float* cams    = (const float*)d_in[3];
    const float* pts     = (const float*)d_in[4];

    int n   = in_sizes[1];  // N_OBS
    int ncw = in_sizes[3];  // N_CAM * 10

    int threads = 1024;
    int per_block = threads * 4;
    int blocks = (n + per_block - 1) / per_block;

    reproj_kernel<<<blocks, threads, 0, stream>>>(
        (const f32x4*)p2d, cam_idx, pt_idx, cams, pts,
        (f32x4*)d_out, n, ncw);
}

// Round 8
// 132.782 us; speedup vs baseline: 1.4613x; 1.0373x over previous
//
#include <hip/hip_runtime.h>

// Reprojection residual for bundle adjustment.
// out[i] = project(points_3d[pt_idx[i]], camera_params[cam_idx[i]]) - points_2d[i]
//
// NUMERICS: harness reference is float64; output is amplified ~proj^5 with
// |Z| down to ~1e-4, so the projection runs in double precision and only the
// final residual rounds to fp32 (absmax 3.60288e16 vs threshold 9.9e16,
// passing since round 2). The f64 op sequence below is frozen.
//
// ROUND 8: cross-iteration software pipelining + persistent blocks.
//   - 512 persistent blocks (2/CU, the 80-KB-LDS max) x 1024 threads,
//     grid-stride over obs pairs: camera table staged 512x not 977x,
//     no ragged-tail imbalance (r7 occupancy 72%).
//   - software pipeline: iteration k+1's index/obs/point loads are issued
//     BEFORE iteration k's f64 compute; the ~600-900 cy gather round-trip
//     hides under ~1.7K cy of compute instead of serializing (r7's
//     per-thread batching still stalled at one vmcnt before any compute).
//   - keep r6 winners: LDS cams, 3-dword point gather (packed-x4 tested
//     slower, r4), NT streaming loads, plain cached stores.
//
// Inputs (setup_inputs order):
//   d_in[0] points_2d      float32 (N_OBS, 2)
//   d_in[1] camera_indices int32   (N_OBS,)
//   d_in[2] point_indices  int32   (N_OBS,)
//   d_in[3] camera_params  float32 (N_CAM, 10)  [qw qx qy qz tx ty tz f k1 k2]
//   d_in[4] points_3d      float32 (N_PTS, 3)
// Output: float32 (N_OBS, 2)

typedef __attribute__((ext_vector_type(4))) float f32x4;
typedef __attribute__((ext_vector_type(2))) int   i32x2;

#define MAX_CAM_WORDS 20000   // 2000 cameras * 10 floats = 80 KB LDS

// f64 projection; camera params from LDS. Frozen arithmetic sequence.
__device__ __forceinline__ float2 project_one(
    const float* lds_cams, int ci,
    float pxf, float pyf, float pzf,
    float obsx, float obsy)
{
    const float2* cl = reinterpret_cast<const float2*>(lds_cams + ci * 10);
    float2 c01 = cl[0];  // qw qx
    float2 c23 = cl[1];  // qy qz
    float2 c45 = cl[2];  // tx ty
    float2 c67 = cl[3];  // tz f
    float2 c89 = cl[4];  // k1 k2

    double px = (double)pxf, py = (double)pyf, pz = (double)pzf;
    double qw = (double)c01.x, qx = (double)c01.y;
    double qy = (double)c23.x, qz = (double)c23.y;

    double nrm2 = qw * qw + qx * qx + qy * qy + qz * qz;
    double s = 1.0 / sqrt(nrm2);
    double w  = qw * s;
    double vx = qx * s, vy = qy * s, vz = qz * s;

    double tx = (vy * pz - vz * py) + w * px;
    double ty = (vz * px - vx * pz) + w * py;
    double tz = (vx * py - vy * px) + w * pz;

    double X = (px + 2.0 * (vy * tz - vz * ty)) + (double)c45.x;
    double Y = (py + 2.0 * (vz * tx - vx * tz)) + (double)c45.y;
    double Z = (pz + 2.0 * (vx * ty - vy * tx)) + (double)c67.x;

    double rz  = 1.0 / Z;
    double prx = -X * rz;
    double pry = -Y * rz;

    double f  = (double)c67.y;
    double k1 = (double)c89.x, k2 = (double)c89.y;

    double nn = prx * prx + pry * pry;
    double r  = 1.0 + k1 * nn + k2 * nn * nn;
    double rf = r * f;

    float2 o;
    o.x = (float)(prx * rf - (double)obsx);
    o.y = (float)(pry * rf - (double)obsy);
    return o;
}

__global__ __launch_bounds__(1024, 8) void reproj_kernel(
    const f32x4*  __restrict__ p2d4,      // 2 observations per float4
    const int*    __restrict__ cam_idx,
    const int*    __restrict__ pt_idx,
    const float*  __restrict__ cams,
    const float*  __restrict__ pts,       // raw (N_PTS,3) float32
    f32x4*        __restrict__ out4,
    int n, int ncam_words)
{
    __shared__ float lds_cams[MAX_CAM_WORDS];

    // cooperative stage: 80 KB, coalesced float4 loads + b128 LDS writes
    {
        int nv = ncam_words >> 2;
        if (nv > (MAX_CAM_WORDS >> 2)) nv = MAX_CAM_WORDS >> 2;
        const f32x4* src = reinterpret_cast<const f32x4*>(cams);
        f32x4* dst = reinterpret_cast<f32x4*>(lds_cams);
        for (int j = threadIdx.x; j < nv; j += blockDim.x)
            dst[j] = src[j];
        for (int j = (nv << 2) + threadIdx.x; j < ncam_words && j < MAX_CAM_WORDS;
             j += blockDim.x)
            lds_cams[j] = cams[j];
    }
    __syncthreads();

    const int stride = gridDim.x * blockDim.x * 2;   // obs per sweep
    int i = (blockIdx.x * blockDim.x + threadIdx.x) * 2;

    // ---- pipeline prologue: load iteration-0 inputs ----
    i32x2 ci, pi;
    f32x4 ob;
    float ax, ay, az, bx, by, bz;
    if (i + 1 < n) {
        ci = __builtin_nontemporal_load(
            reinterpret_cast<const i32x2*>(cam_idx + i));
        pi = __builtin_nontemporal_load(
            reinterpret_cast<const i32x2*>(pt_idx + i));
        ob = __builtin_nontemporal_load(p2d4 + (i >> 1));
        const float* pA = pts + (size_t)pi.x * 3;
        const float* pB = pts + (size_t)pi.y * 3;
        ax = pA[0]; ay = pA[1]; az = pA[2];
        bx = pB[0]; by = pB[1]; bz = pB[2];
    }

    while (i + 1 < n) {
        int j = i + stride;

        // ---- issue next iteration's loads BEFORE current compute ----
        i32x2 cin, pin;
        f32x4 obn;
        float nax, nay, naz, nbx, nby, nbz;
        bool nhave = (j + 1 < n);
        if (nhave) {
            cin = __builtin_nontemporal_load(
                reinterpret_cast<const i32x2*>(cam_idx + j));
            pin = __builtin_nontemporal_load(
                reinterpret_cast<const i32x2*>(pt_idx + j));
            obn = __builtin_nontemporal_load(p2d4 + (j >> 1));
            const float* pA = pts + (size_t)pin.x * 3;
            const float* pB = pts + (size_t)pin.y * 3;
            nax = pA[0]; nay = pA[1]; naz = pA[2];
            nbx = pB[0]; nby = pB[1]; nbz = pB[2];
        }

        // ---- compute current iteration (hides next loads' latency) ----
        float2 o0 = project_one(lds_cams, ci.x, ax, ay, az, ob.x, ob.y);
        float2 o1 = project_one(lds_cams, ci.y, bx, by, bz, ob.z, ob.w);
        f32x4 ov = {o0.x, o0.y, o1.x, o1.y};
        out4[i >> 1] = ov;   // plain cached store: L2 write-combines

        // ---- rotate pipeline ----
        i = j;
        if (nhave) {
            ci = cin; pi = pin; ob = obn;
            ax = nax; ay = nay; az = naz;
            bx = nbx; by = nby; bz = nbz;
        }
    }

    // tail: single trailing observation (odd n)
    if (i < n) {
        int cis = cam_idx[i];
        int pis = pt_idx[i];
        const float* pA = pts + (size_t)pis * 3;
        const float* p2 = reinterpret_cast<const float*>(p2d4);
        float2 o = project_one(lds_cams, cis, pA[0], pA[1], pA[2],
                               p2[2 * i], p2[2 * i + 1]);
        float* po = reinterpret_cast<float*>(out4);
        po[2 * i]     = o.x;
        po[2 * i + 1] = o.y;
    }
}

extern "C" void kernel_launch(void* const* d_in, const int* in_sizes, int n_in,
                              void* d_out, int out_size, void* d_ws, size_t ws_size,
                              hipStream_t stream) {
    const float* p2d     = (const float*)d_in[0];
    const int*   cam_idx = (const int*)d_in[1];
    const int*   pt_idx  = (const int*)d_in[2];
    const float* cams    = (const float*)d_in[3];
    const float* pts     = (const float*)d_in[4];

    int n   = in_sizes[1];  // N_OBS
    int ncw = in_sizes[3];  // N_CAM * 10

    int threads = 1024;
    // persistent: 2 blocks/CU (80-KB LDS max) on 256 CUs
    int blocks = 512;
    int need = (n + threads * 2 - 1) / (threads * 2);
    if (need < blocks) blocks = need;
    if (blocks < 1) blocks = 1;

    reproj_kernel<<<blocks, threads, 0, stream>>>(
        (const f32x4*)p2d, cam_idx, pt_idx, cams, pts,
        (f32x4*)d_out, n, ncw);
}